// Round 1
// 4362.106 us; speedup vs baseline: 1.0061x; 1.0061x over previous
//
#include <hip/hip_runtime.h>

// LSTM char-RNN scan: B=512, SEQ=1024, UNITS=256, NUM_CHARS=128. fp32 in/out.
// Round 15: kill per-step L2 latency + halve barriers.
//   - 6 REG + 2 LDS tiles per wave: FULL W_h residency (stream tile gone).
//     WR = 192 regs; peak ~254 of the 256/wave cap at 8 waves/WG. Spill
//     signature to watch: FETCH/WRITE_SIZE at GB scale.
//   - AH double-buffered (2 planes, 16 KB): ONE __syncthreads per step
//     (write plane p^1 cannot race plane-p reads). Update compute+write
//     merged (hh staging regs dropped).
//   - Token int4 prefetched one step ahead; Wxp float4 gathers issued
//     OUTSIDE the quad<2 branch (same scheduling region as MFMA loop) so
//     the compiler can hide the L2 gather under MFMA issue. Quads 2/3
//     duplicate quads 0/1 addresses (TCC dedup, no correctness impact).
// Numerics frozen: W_h bf16 RNE, h bf16 RNE, c/gates fp32 (absmax 4.8828e-4).

#define U       256
#define SEQ     1024
#define NC      128
#define GDIM    1024
#define BCR     8          // batch rows per WG
#define THREADS 512        // 8 waves

typedef short bf16x8 __attribute__((ext_vector_type(8)));
typedef float f32x4  __attribute__((ext_vector_type(4)));

#define WP_OFF   0                        // 512 KB packed W_h
#define WXP_OFF  (512*1024)               // 512 KB packed Wx+bias
#define WS_NEED  (1024*1024)

__device__ __forceinline__ float sig_(float x)  { return 1.0f / (1.0f + __expf(-x)); }
__device__ __forceinline__ float tanh_(float x) { return 1.0f - 2.0f / (__expf(2.0f * x) + 1.0f); }
__device__ __forceinline__ unsigned rne16(float f) {
    union { float f; unsigned u; } v; v.f = f;
    return (v.u + 0x7FFFu + ((v.u >> 16) & 1u)) >> 16;
}
__device__ __forceinline__ float u2f(unsigned u) {
    union { unsigned u; float f; } v; v.u = u; return v.f;
}

// ---- pack W_h into MFMA B-frag order (validated rounds 5-14) ----
// Wp[(nt*8+kt)*64 + lane]: col = nt*16+(lane&15); k = kt*32+(lane>>4)*8 + j,
// dword d packs (k=2d lo, k=2d+1 hi).
__global__ __launch_bounds__(256)
void pack_wh(const float* __restrict__ Wh, uint4* __restrict__ Wp) {
    int i    = blockIdx.x * 256 + threadIdx.x;   // [0, 32768)
    int lane = i & 63;
    int kt   = (i >> 6) & 7;
    int nt   = i >> 9;
    int col  = nt * 16 + (lane & 15);
    int k0   = kt * 32 + ((lane >> 4) * 8);
    const float* base = Wh + (size_t)k0 * GDIM + col;
    unsigned p0 = rne16(base[0 * GDIM]) | (rne16(base[1 * GDIM]) << 16);
    unsigned p1 = rne16(base[2 * GDIM]) | (rne16(base[3 * GDIM]) << 16);
    unsigned p2 = rne16(base[4 * GDIM]) | (rne16(base[5 * GDIM]) << 16);
    unsigned p3 = rne16(base[6 * GDIM]) | (rne16(base[7 * GDIM]) << 16);
    Wp[i] = make_uint4(p0, p1, p2, p3);
}

// ---- pack Wx + bias (+forget_bias) into float4 per (x, unit) ----
__global__ __launch_bounds__(256)
void pack_wx(const float* __restrict__ Wx, const float* __restrict__ bias,
             float4* __restrict__ Wxp) {
    int i = blockIdx.x * 256 + threadIdx.x;      // [0, 32768)
    int x = i >> 8, u = i & 255;
    const float* r = Wx + (size_t)x * GDIM;
    Wxp[i] = make_float4(r[u]       + bias[u],
                         r[256 + u] + bias[256 + u],
                         r[512 + u] + bias[512 + u] + 1.0f,   // forget_bias
                         r[768 + u] + bias[768 + u]);
}

__global__ __launch_bounds__(THREADS, 2)
void lstm_w64(const int* __restrict__ tokens,
              const uint4* __restrict__ Wp,     // packed W_h (ws)
              const float4* __restrict__ Wxp,   // packed Wx+b (ws)
              const float* __restrict__ Wd,     // [256,128]
              const float* __restrict__ bd,     // [128]
              float* __restrict__ out)          // [512,128]
{
    __shared__ uint4 LW[16][8][64];              // 128 KB  W in LDS (2 nt/wave)
    __shared__ __align__(16) short AH[2][8][64][8]; // 16 KB h bf16, double-buffered
    __shared__ int   tokw[64][8];                // 2 KB   64-step token window

    const int tid  = threadIdx.x;
    const int wv   = tid >> 6;        // wave 0..7
    const int lane = tid & 63;
    const int m    = lane & 15;
    const int quad = lane >> 4;
    const int r0   = blockIdx.x * BCR;
    const int mrow = (quad & 1) * 4;  // rows this lane handles (quads 2/3 mirror 0/1)

    // wave wv owns unit blocks {wv, 8+wv} (32 units), all 4 gates:
    // nt set = {wv, 8+wv, 16+wv, 24+wv, 32+wv, 40+wv, 48+wv, 56+wv}.
    // REG: first 6 (192 regs).  LDS: {48+wv, 56+wv}.  No stream.
    bf16x8 WR[6][8];
    #pragma unroll
    for (int jj = 0; jj < 6; ++jj)
        #pragma unroll
        for (int kt = 0; kt < 8; ++kt) {
            union { uint4 u; bf16x8 v; } c;
            c.u = Wp[((size_t)((wv + 8 * jj) * 8 + kt)) * 64 + lane];
            WR[jj][kt] = c.v;
        }
    const int slA = 2 * wv;
    #pragma unroll
    for (int kt = 0; kt < 8; ++kt) {
        LW[slA][kt][lane]     = Wp[((size_t)((48 + wv) * 8 + kt)) * 64 + lane];
        LW[slA + 1][kt][lane] = Wp[((size_t)((56 + wv) * 8 + kt)) * 64 + lane];
    }
    for (int i = tid; i < 4096; i += THREADS)    // zero both A planes (as ints)
        ((int*)AH)[i] = 0;

    // update-phase constants: lane (quad<2) updates rows quad*4..quad*4+3 of
    // units u0 = wv*16+m and u1 = (8+wv)*16+m.
    float cst[2][4] = {{0.f,0.f,0.f,0.f},{0.f,0.f,0.f,0.f}};
    const int u0 = wv * 16 + m;
    const int u1 = (8 + wv) * 16 + m;
    const int kt0 = u0 >> 5, qa0 = (u0 >> 3) & 3, j0 = u0 & 7;
    const int kt1 = u1 >> 5, qa1 = (u1 >> 3) & 3, j1 = u1 & 7;

    union { int4 v; int a[4]; } xq;   // tokens for this step (rows mrow..mrow+3)

    __syncthreads();

    for (int t = 0; t < SEQ; ++t) {
        if ((t & 63) == 0) {           // refresh token window
            tokw[tid >> 3][tid & 7] =
                tokens[(size_t)(r0 + (tid & 7)) * SEQ + t + (tid >> 3)];
            __syncthreads();
            xq.v = *(const int4*)&tokw[0][mrow];
        }
        const int p = t & 1;

        // ---- MFMA phase: 8 acc x 8 kt (all operands resident) ----
        // acc: [0]=iA [1]=iB [2]=jA [3]=jB [4]=fA [5]=fB [6]=oA(LDS) [7]=oB(LDS)
        f32x4 acc[8];
        #pragma unroll
        for (int j = 0; j < 8; ++j) acc[j] = (f32x4){0.f, 0.f, 0.f, 0.f};

        #pragma unroll
        for (int kt = 0; kt < 8; ++kt) {
            bf16x8 ah = *(const bf16x8*)&AH[p][kt][lane][0];
            union { uint4 u; bf16x8 v; } l0, l1;
            l0.u = LW[slA][kt][lane];
            l1.u = LW[slA + 1][kt][lane];
            acc[0] = __builtin_amdgcn_mfma_f32_16x16x32_bf16(ah, WR[0][kt], acc[0], 0, 0, 0);
            acc[1] = __builtin_amdgcn_mfma_f32_16x16x32_bf16(ah, WR[1][kt], acc[1], 0, 0, 0);
            acc[2] = __builtin_amdgcn_mfma_f32_16x16x32_bf16(ah, WR[2][kt], acc[2], 0, 0, 0);
            acc[3] = __builtin_amdgcn_mfma_f32_16x16x32_bf16(ah, WR[3][kt], acc[3], 0, 0, 0);
            acc[4] = __builtin_amdgcn_mfma_f32_16x16x32_bf16(ah, WR[4][kt], acc[4], 0, 0, 0);
            acc[5] = __builtin_amdgcn_mfma_f32_16x16x32_bf16(ah, WR[5][kt], acc[5], 0, 0, 0);
            acc[6] = __builtin_amdgcn_mfma_f32_16x16x32_bf16(ah, l0.v, acc[6], 0, 0, 0);
            acc[7] = __builtin_amdgcn_mfma_f32_16x16x32_bf16(ah, l1.v, acc[7], 0, 0, 0);
        }

        // ---- Wxp gathers for this step: issued outside the masked branch so
        // the scheduler can overlap them with the MFMA phase above ----
        float4 wxa[4], wxb[4];
        #pragma unroll
        for (int ri = 0; ri < 4; ++ri) {
            wxa[ri] = Wxp[(size_t)xq.a[ri] * 256 + u0];
            wxb[ri] = Wxp[(size_t)xq.a[ri] * 256 + u1];
        }

        // ---- in-register LSTM update + direct AH write (plane p^1) ----
        if (quad < 2) {
            #pragma unroll
            for (int ri = 0; ri < 4; ++ri) {
                const int row = quad * 4 + ri;
                // unit block A: gates i=acc[0], j=acc[2], f=acc[4], o=acc[6]
                {
                    float gi = acc[0][ri] + wxa[ri].x;
                    float gj = acc[2][ri] + wxa[ri].y;
                    float gf = acc[4][ri] + wxa[ri].z;    // forget_bias folded
                    float go = acc[6][ri] + wxa[ri].w;
                    float c  = cst[0][ri];
                    c = c * sig_(gf) + sig_(gi) * tanh_(gj);
                    cst[0][ri] = c;
                    AH[p ^ 1][kt0][qa0 * 16 + row][j0] =
                        (short)rne16(tanh_(c) * sig_(go));
                }
                // unit block B: gates i=acc[1], j=acc[3], f=acc[5], o=acc[7]
                {
                    float gi = acc[1][ri] + wxb[ri].x;
                    float gj = acc[3][ri] + wxb[ri].y;
                    float gf = acc[5][ri] + wxb[ri].z;
                    float go = acc[7][ri] + wxb[ri].w;
                    float c  = cst[1][ri];
                    c = c * sig_(gf) + sig_(gi) * tanh_(gj);
                    cst[1][ri] = c;
                    AH[p ^ 1][kt1][qa1 * 16 + row][j1] =
                        (short)rne16(tanh_(c) * sig_(go));
                }
            }
        }

        // prefetch next step's tokens (window-interior only)
        if (((t + 1) & 63) != 0)
            xq.v = *(const int4*)&tokw[(t + 1) & 63][mrow];

        __syncthreads();       // single barrier: plane p^1 now visible
    }

    // ---- final dense (h is bf16 in plane 0; 8 rows x 128 cols) ----
    for (int o = tid; o < BCR * NC; o += THREADS) {
        const int r = o >> 7;
        const int n = o & (NC - 1);
        float sum = bd[n];
        #pragma unroll 4
        for (int k = 0; k < U; ++k) {
            float hk = u2f(((unsigned)(unsigned short)
                            AH[0][k >> 5][((k >> 3) & 3) * 16 + r][k & 7]) << 16);
            sum = fmaf(hk, Wd[k * NC + n], sum);
        }
        out[(size_t)(r0 + r) * NC + n] = sum;
    }
}

// ================= fallback: round-5 streaming kernel (proven 7.6 ms) =========
__global__ __launch_bounds__(256)
void pack_kq(const float* __restrict__ Wh, uint4* __restrict__ Whb) {
    int idx = blockIdx.x * 256 + threadIdx.x;
    int kq  = idx >> 10;
    int c   = idx & 1023;
    const float* base = Wh + (size_t)(kq * 8) * GDIM + c;
    unsigned p0 = rne16(base[0 * GDIM]) | (rne16(base[1 * GDIM]) << 16);
    unsigned p1 = rne16(base[2 * GDIM]) | (rne16(base[3 * GDIM]) << 16);
    unsigned p2 = rne16(base[4 * GDIM]) | (rne16(base[5 * GDIM]) << 16);
    unsigned p3 = rne16(base[6 * GDIM]) | (rne16(base[7 * GDIM]) << 16);
    Whb[idx] = make_uint4(p0, p1, p2, p3);
}

__global__ __launch_bounds__(1024, 4)
void lstm_stream(const int* __restrict__ tokens, const float* __restrict__ Wx,
                 const uint4* __restrict__ Whb, const float* __restrict__ bias,
                 const float* __restrict__ Wd, const float* __restrict__ bd,
                 float* __restrict__ out)
{
    __shared__ float h32[2][U];
    __shared__ float G2[GDIM][2];
    __shared__ int   tok[2][SEQ];
    const int tid = threadIdx.x;
    const int r0  = blockIdx.x * 2;
    for (int i = tid; i < 2 * SEQ; i += 1024)
        ((int*)tok)[i] = tokens[r0 * SEQ + i];
    if (tid < 2 * U) ((float*)h32)[tid] = 0.0f;
    const float b_c = bias[tid];
    float c_state = 0.0f;
    const int ur = tid >> 8, uu = tid & 255;
    __syncthreads();
    const uint4* wp = Whb + tid;
    for (int t = 0; t < SEQ; ++t) {
        const int x0 = tok[0][t], x1 = tok[1][t];
        float a0e = Wx[x0 * GDIM + tid] + b_c;
        float a1e = Wx[x1 * GDIM + tid] + b_c;
        float a0o = 0.f, a1o = 0.f;
        #pragma unroll 4
        for (int kq = 0; kq < 32; ++kq) {
            float4 h0a = *(const float4*)&h32[0][kq * 8];
            float4 h0b = *(const float4*)&h32[0][kq * 8 + 4];
            float4 h1a = *(const float4*)&h32[1][kq * 8];
            float4 h1b = *(const float4*)&h32[1][kq * 8 + 4];
            uint4 wv2 = wp[kq << 10];
            float we0 = u2f(wv2.x << 16), wo0 = u2f(wv2.x & 0xffff0000u);
            float we1 = u2f(wv2.y << 16), wo1 = u2f(wv2.y & 0xffff0000u);
            float we2 = u2f(wv2.z << 16), wo2 = u2f(wv2.z & 0xffff0000u);
            float we3 = u2f(wv2.w << 16), wo3 = u2f(wv2.w & 0xffff0000u);
            a0e = fmaf(h0a.x, we0, a0e); a0o = fmaf(h0a.y, wo0, a0o);
            a1e = fmaf(h1a.x, we0, a1e); a1o = fmaf(h1a.y, wo0, a1o);
            a0e = fmaf(h0a.z, we1, a0e); a0o = fmaf(h0a.w, wo1, a0o);
            a1e = fmaf(h1a.z, we1, a1e); a1o = fmaf(h1a.w, wo1, a1o);
            a0e = fmaf(h0b.x, we2, a0e); a0o = fmaf(h0b.y, wo2, a0o);
            a1e = fmaf(h1b.x, we2, a1e); a1o = fmaf(h1b.y, wo2, a1o);
            a0e = fmaf(h0b.z, we3, a0e); a0o = fmaf(h0b.w, wo3, a0o);
            a1e = fmaf(h1b.z, we3, a1e); a1o = fmaf(h1b.w, wo3, a1o);
        }
        *(float2*)&G2[tid][0] = make_float2(a0e + a0o, a1e + a1o);
        __syncthreads();
        if (tid < 2 * U) {
            float gi = G2[uu][ur], gj = G2[U + uu][ur];
            float gf = G2[2 * U + uu][ur], go = G2[3 * U + uu][ur];
            c_state = c_state * sig_(gf + 1.0f) + sig_(gi) * tanh_(gj);
            h32[ur][uu] = tanh_(c_state) * sig_(go);
        }
        __syncthreads();
    }
    if (tid < 2 * NC) {
        const int r = tid >> 7, n = tid & (NC - 1);
        float sum = bd[n];
        #pragma unroll 4
        for (int k = 0; k < U; ++k)
            sum = fmaf(h32[r][k], Wd[k * NC + n], sum);
        out[(r0 + r) * NC + n] = sum;
    }
}

extern "C" void kernel_launch(void* const* d_in, const int* in_sizes, int n_in,
                              void* d_out, int out_size, void* d_ws, size_t ws_size,
                              hipStream_t stream) {
    const int*   tokens = (const int*)d_in[0];
    const float* Wx     = (const float*)d_in[1];
    const float* Wh     = (const float*)d_in[2];
    const float* bias   = (const float*)d_in[3];
    const float* Wd     = (const float*)d_in[4];
    const float* bd     = (const float*)d_in[5];
    float*       out    = (float*)d_out;

    if (ws_size >= (size_t)WS_NEED) {
        uint4*  Wp  = (uint4*)((char*)d_ws + WP_OFF);
        float4* Wxp = (float4*)((char*)d_ws + WXP_OFF);
        pack_wh<<<128, 256, 0, stream>>>(Wh, Wp);
        pack_wx<<<128, 256, 0, stream>>>(Wx, bias, Wxp);
        lstm_w64<<<512 / BCR, THREADS, 0, stream>>>(tokens, Wp, Wxp, Wd, bd, out);
    } else {
        uint4* Whb = (uint4*)d_ws;
        pack_kq<<<128, 256, 0, stream>>>(Wh, Whb);
        lstm_stream<<<256, 1024, 0, stream>>>(tokens, Wx, Whb, bias, Wd, bd, out);
    }
}

// Round 2
// 1905.923 us; speedup vs baseline: 2.3027x; 2.2887x over previous
//
#include <hip/hip_runtime.h>

// LSTM char-RNN scan: B=512, SEQ=1024, UNITS=256, NUM_CHARS=128. fp32 in/out.
// Round 16: 128-CU variant via row-spread fragment mapping.
//   Post-mortem r15: step = 10,222 cy; per SIMD ~2050 cy MFMA (pipe, fixed)
//   + ~2000 cy VALU (update: 8 cells/lane, quads 0/1 only) + ~60% stall.
//   MFMA/CU/step is FIXED by W_h replication; update VALU scales with
//   cells/lane. Fix: BCR=4 and place the 4 batch rows at M-rows {0,4,8,12}
//   so each quad owns one row at acc[.][0]:
//     - 2 cells/lane (was 8): update issue /4, all 64 lanes useful.
//     - 128 WGs -> 128 CUs active (2x r15), grid 512/4.
//     - 2 Wxp float4 gathers/lane (was 8), hoisted BEFORE the MFMA loop so
//       L2 latency hides under ~2000 cy of MFMA issue (vmcnt waits at use).
//     - token window shrinks to [64][4]; scalar int prefetch.
//   M-tile now 4/16 rows used: wasted MFMA FLOPs, but matrix-pipe time per
//   step is unchanged - we are buying VALU time and CU count.
// Numerics frozen: W_h bf16 RNE, h bf16 RNE, c/gates fp32 (absmax 4.8828e-4).

#define U       256
#define SEQ     1024
#define NC      128
#define GDIM    1024
#define BCR     4          // batch rows per WG (at M-rows 0,4,8,12)
#define THREADS 512        // 8 waves

typedef short bf16x8 __attribute__((ext_vector_type(8)));
typedef float f32x4  __attribute__((ext_vector_type(4)));

#define WP_OFF   0                        // 512 KB packed W_h
#define WXP_OFF  (512*1024)               // 512 KB packed Wx+bias
#define WS_NEED  (1024*1024)

__device__ __forceinline__ float sig_(float x)  { return 1.0f / (1.0f + __expf(-x)); }
__device__ __forceinline__ float tanh_(float x) { return 1.0f - 2.0f / (__expf(2.0f * x) + 1.0f); }
__device__ __forceinline__ unsigned rne16(float f) {
    union { float f; unsigned u; } v; v.f = f;
    return (v.u + 0x7FFFu + ((v.u >> 16) & 1u)) >> 16;
}
__device__ __forceinline__ float u2f(unsigned u) {
    union { unsigned u; float f; } v; v.u = u; return v.f;
}

// ---- pack W_h into MFMA B-frag order (validated rounds 5-15) ----
// Wp[(nt*8+kt)*64 + lane]: col = nt*16+(lane&15); k = kt*32+(lane>>4)*8 + j,
// dword d packs (k=2d lo, k=2d+1 hi).
__global__ __launch_bounds__(256)
void pack_wh(const float* __restrict__ Wh, uint4* __restrict__ Wp) {
    int i    = blockIdx.x * 256 + threadIdx.x;   // [0, 32768)
    int lane = i & 63;
    int kt   = (i >> 6) & 7;
    int nt   = i >> 9;
    int col  = nt * 16 + (lane & 15);
    int k0   = kt * 32 + ((lane >> 4) * 8);
    const float* base = Wh + (size_t)k0 * GDIM + col;
    unsigned p0 = rne16(base[0 * GDIM]) | (rne16(base[1 * GDIM]) << 16);
    unsigned p1 = rne16(base[2 * GDIM]) | (rne16(base[3 * GDIM]) << 16);
    unsigned p2 = rne16(base[4 * GDIM]) | (rne16(base[5 * GDIM]) << 16);
    unsigned p3 = rne16(base[6 * GDIM]) | (rne16(base[7 * GDIM]) << 16);
    Wp[i] = make_uint4(p0, p1, p2, p3);
}

// ---- pack Wx + bias (+forget_bias) into float4 per (x, unit) ----
__global__ __launch_bounds__(256)
void pack_wx(const float* __restrict__ Wx, const float* __restrict__ bias,
             float4* __restrict__ Wxp) {
    int i = blockIdx.x * 256 + threadIdx.x;      // [0, 32768)
    int x = i >> 8, u = i & 255;
    const float* r = Wx + (size_t)x * GDIM;
    Wxp[i] = make_float4(r[u]       + bias[u],
                         r[256 + u] + bias[256 + u],
                         r[512 + u] + bias[512 + u] + 1.0f,   // forget_bias
                         r[768 + u] + bias[768 + u]);
}

__global__ __launch_bounds__(THREADS, 2)
void lstm_w128(const int* __restrict__ tokens,
               const uint4* __restrict__ Wp,     // packed W_h (ws)
               const float4* __restrict__ Wxp,   // packed Wx+b (ws)
               const float* __restrict__ Wd,     // [256,128]
               const float* __restrict__ bd,     // [128]
               float* __restrict__ out)          // [512,128]
{
    __shared__ uint4 LW[16][8][64];              // 128 KB  W in LDS (2 nt/wave)
    __shared__ __align__(16) short AH[2][8][64][8]; // 16 KB h bf16, double-buffered
    __shared__ int   tokw[64][4];                // 1 KB   64-step token window

    const int tid  = threadIdx.x;
    const int wv   = tid >> 6;        // wave 0..7
    const int lane = tid & 63;
    const int m    = lane & 15;
    const int quad = lane >> 4;
    const int r0   = blockIdx.x * BCR;

    // wave wv owns unit blocks {wv, 8+wv} (32 units), all 4 gates:
    // nt set = {wv, 8+wv, 16+wv, 24+wv, 32+wv, 40+wv, 48+wv, 56+wv}.
    // REG: first 6 (192 regs).  LDS: {48+wv, 56+wv}.
    bf16x8 WR[6][8];
    #pragma unroll
    for (int jj = 0; jj < 6; ++jj)
        #pragma unroll
        for (int kt = 0; kt < 8; ++kt) {
            union { uint4 u; bf16x8 v; } c;
            c.u = Wp[((size_t)((wv + 8 * jj) * 8 + kt)) * 64 + lane];
            WR[jj][kt] = c.v;
        }
    const int slA = 2 * wv;
    #pragma unroll
    for (int kt = 0; kt < 8; ++kt) {
        LW[slA][kt][lane]     = Wp[((size_t)((48 + wv) * 8 + kt)) * 64 + lane];
        LW[slA + 1][kt][lane] = Wp[((size_t)((56 + wv) * 8 + kt)) * 64 + lane];
    }
    for (int i = tid; i < 4096; i += THREADS)    // zero both A planes (as ints)
        ((int*)AH)[i] = 0;

    // update-phase constants: EVERY lane updates batch row `quad` (M-row
    // 4*quad, i.e. acc[.][0]) of units u0 = wv*16+m and u1 = (8+wv)*16+m.
    float cst0 = 0.f, cst1 = 0.f;
    const int u0 = wv * 16 + m;
    const int u1 = (8 + wv) * 16 + m;
    const int kt0 = u0 >> 5, qa0 = (u0 >> 3) & 3, j0 = u0 & 7;
    const int kt1 = u1 >> 5, qa1 = (u1 >> 3) & 3, j1 = u1 & 7;
    const int myrow = 4 * quad;       // M-row holding this lane's batch row

    int xq = 0;                       // this step's token for batch row `quad`

    __syncthreads();

    for (int t = 0; t < SEQ; ++t) {
        if ((t & 63) == 0) {           // refresh token window (64 x 4 ints)
            if (tid < 256)
                tokw[tid >> 2][tid & 3] =
                    tokens[(size_t)(r0 + (tid & 3)) * SEQ + t + (tid >> 2)];
            __syncthreads();
            xq = tokw[0][quad];
        }
        const int p = t & 1;

        // ---- Wxp gathers for THIS step, issued before MFMA so the ~300 cy
        // L2 latency hides under ~2000 cy of matrix-pipe issue ----
        const float4 wxa = Wxp[(size_t)xq * 256 + u0];
        const float4 wxb = Wxp[(size_t)xq * 256 + u1];

        // ---- MFMA phase: 8 acc x 8 kt (all operands resident) ----
        // acc: [0]=iA [1]=iB [2]=jA [3]=jB [4]=fA [5]=fB [6]=oA(LDS) [7]=oB(LDS)
        f32x4 acc[8];
        #pragma unroll
        for (int j = 0; j < 8; ++j) acc[j] = (f32x4){0.f, 0.f, 0.f, 0.f};

        #pragma unroll
        for (int kt = 0; kt < 8; ++kt) {
            bf16x8 ah = *(const bf16x8*)&AH[p][kt][lane][0];
            union { uint4 u; bf16x8 v; } l0, l1;
            l0.u = LW[slA][kt][lane];
            l1.u = LW[slA + 1][kt][lane];
            acc[0] = __builtin_amdgcn_mfma_f32_16x16x32_bf16(ah, WR[0][kt], acc[0], 0, 0, 0);
            acc[1] = __builtin_amdgcn_mfma_f32_16x16x32_bf16(ah, WR[1][kt], acc[1], 0, 0, 0);
            acc[2] = __builtin_amdgcn_mfma_f32_16x16x32_bf16(ah, WR[2][kt], acc[2], 0, 0, 0);
            acc[3] = __builtin_amdgcn_mfma_f32_16x16x32_bf16(ah, WR[3][kt], acc[3], 0, 0, 0);
            acc[4] = __builtin_amdgcn_mfma_f32_16x16x32_bf16(ah, WR[4][kt], acc[4], 0, 0, 0);
            acc[5] = __builtin_amdgcn_mfma_f32_16x16x32_bf16(ah, WR[5][kt], acc[5], 0, 0, 0);
            acc[6] = __builtin_amdgcn_mfma_f32_16x16x32_bf16(ah, l0.v, acc[6], 0, 0, 0);
            acc[7] = __builtin_amdgcn_mfma_f32_16x16x32_bf16(ah, l1.v, acc[7], 0, 0, 0);
        }

        // ---- in-register LSTM update: 2 cells/lane, direct AH write (p^1) ----
        // unit block A: gates i=acc[0], j=acc[2], f=acc[4], o=acc[6]
        {
            float gi = acc[0][0] + wxa.x;
            float gj = acc[2][0] + wxa.y;
            float gf = acc[4][0] + wxa.z;    // forget_bias folded
            float go = acc[6][0] + wxa.w;
            float c  = cst0;
            c = c * sig_(gf) + sig_(gi) * tanh_(gj);
            cst0 = c;
            AH[p ^ 1][kt0][qa0 * 16 + myrow][j0] =
                (short)rne16(tanh_(c) * sig_(go));
        }
        // unit block B: gates i=acc[1], j=acc[3], f=acc[5], o=acc[7]
        {
            float gi = acc[1][0] + wxb.x;
            float gj = acc[3][0] + wxb.y;
            float gf = acc[5][0] + wxb.z;
            float go = acc[7][0] + wxb.w;
            float c  = cst1;
            c = c * sig_(gf) + sig_(gi) * tanh_(gj);
            cst1 = c;
            AH[p ^ 1][kt1][qa1 * 16 + myrow][j1] =
                (short)rne16(tanh_(c) * sig_(go));
        }

        // prefetch next step's token (window-interior only)
        if (((t + 1) & 63) != 0)
            xq = tokw[(t + 1) & 63][quad];

        __syncthreads();       // single barrier: plane p^1 now visible
    }

    // ---- final dense (h is bf16 in plane 0; 4 rows x 128 cols) ----
    // batch row r lives at M-row 4r.
    for (int o = tid; o < BCR * NC; o += THREADS) {
        const int r = o >> 7;
        const int n = o & (NC - 1);
        float sum = bd[n];
        #pragma unroll 4
        for (int k = 0; k < U; ++k) {
            float hk = u2f(((unsigned)(unsigned short)
                            AH[0][k >> 5][((k >> 3) & 3) * 16 + 4 * r][k & 7]) << 16);
            sum = fmaf(hk, Wd[k * NC + n], sum);
        }
        out[(size_t)(r0 + r) * NC + n] = sum;
    }
}

// ================= fallback: round-5 streaming kernel (proven 7.6 ms) =========
__global__ __launch_bounds__(256)
void pack_kq(const float* __restrict__ Wh, uint4* __restrict__ Whb) {
    int idx = blockIdx.x * 256 + threadIdx.x;
    int kq  = idx >> 10;
    int c   = idx & 1023;
    const float* base = Wh + (size_t)(kq * 8) * GDIM + c;
    unsigned p0 = rne16(base[0 * GDIM]) | (rne16(base[1 * GDIM]) << 16);
    unsigned p1 = rne16(base[2 * GDIM]) | (rne16(base[3 * GDIM]) << 16);
    unsigned p2 = rne16(base[4 * GDIM]) | (rne16(base[5 * GDIM]) << 16);
    unsigned p3 = rne16(base[6 * GDIM]) | (rne16(base[7 * GDIM]) << 16);
    Whb[idx] = make_uint4(p0, p1, p2, p3);
}

__global__ __launch_bounds__(1024, 4)
void lstm_stream(const int* __restrict__ tokens, const float* __restrict__ Wx,
                 const uint4* __restrict__ Whb, const float* __restrict__ bias,
                 const float* __restrict__ Wd, const float* __restrict__ bd,
                 float* __restrict__ out)
{
    __shared__ float h32[2][U];
    __shared__ float G2[GDIM][2];
    __shared__ int   tok[2][SEQ];
    const int tid = threadIdx.x;
    const int r0  = blockIdx.x * 2;
    for (int i = tid; i < 2 * SEQ; i += 1024)
        ((int*)tok)[i] = tokens[r0 * SEQ + i];
    if (tid < 2 * U) ((float*)h32)[tid] = 0.0f;
    const float b_c = bias[tid];
    float c_state = 0.0f;
    const int ur = tid >> 8, uu = tid & 255;
    __syncthreads();
    const uint4* wp = Whb + tid;
    for (int t = 0; t < SEQ; ++t) {
        const int x0 = tok[0][t], x1 = tok[1][t];
        float a0e = Wx[x0 * GDIM + tid] + b_c;
        float a1e = Wx[x1 * GDIM + tid] + b_c;
        float a0o = 0.f, a1o = 0.f;
        #pragma unroll 4
        for (int kq = 0; kq < 32; ++kq) {
            float4 h0a = *(const float4*)&h32[0][kq * 8];
            float4 h0b = *(const float4*)&h32[0][kq * 8 + 4];
            float4 h1a = *(const float4*)&h32[1][kq * 8];
            float4 h1b = *(const float4*)&h32[1][kq * 8 + 4];
            uint4 wv2 = wp[kq << 10];
            float we0 = u2f(wv2.x << 16), wo0 = u2f(wv2.x & 0xffff0000u);
            float we1 = u2f(wv2.y << 16), wo1 = u2f(wv2.y & 0xffff0000u);
            float we2 = u2f(wv2.z << 16), wo2 = u2f(wv2.z & 0xffff0000u);
            float we3 = u2f(wv2.w << 16), wo3 = u2f(wv2.w & 0xffff0000u);
            a0e = fmaf(h0a.x, we0, a0e); a0o = fmaf(h0a.y, wo0, a0o);
            a1e = fmaf(h1a.x, we0, a1e); a1o = fmaf(h1a.y, wo0, a1o);
            a0e = fmaf(h0a.z, we1, a0e); a0o = fmaf(h0a.w, wo1, a0o);
            a1e = fmaf(h1a.z, we1, a1e); a1o = fmaf(h1a.w, wo1, a1o);
            a0e = fmaf(h0b.x, we2, a0e); a0o = fmaf(h0b.y, wo2, a0o);
            a1e = fmaf(h1b.x, we2, a1e); a1o = fmaf(h1b.y, wo2, a1o);
            a0e = fmaf(h0b.z, we3, a0e); a0o = fmaf(h0b.w, wo3, a0o);
            a1e = fmaf(h1b.z, we3, a1e); a1o = fmaf(h1b.w, wo3, a1o);
        }
        *(float2*)&G2[tid][0] = make_float2(a0e + a0o, a1e + a1o);
        __syncthreads();
        if (tid < 2 * U) {
            float gi = G2[uu][ur], gj = G2[U + uu][ur];
            float gf = G2[2 * U + uu][ur], go = G2[3 * U + uu][ur];
            c_state = c_state * sig_(gf + 1.0f) + sig_(gi) * tanh_(gj);
            h32[ur][uu] = tanh_(c_state) * sig_(go);
        }
        __syncthreads();
    }
    if (tid < 2 * NC) {
        const int r = tid >> 7, n = tid & (NC - 1);
        float sum = bd[n];
        #pragma unroll 4
        for (int k = 0; k < U; ++k)
            sum = fmaf(h32[r][k], Wd[k * NC + n], sum);
        out[(r0 + r) * NC + n] = sum;
    }
}

extern "C" void kernel_launch(void* const* d_in, const int* in_sizes, int n_in,
                              void* d_out, int out_size, void* d_ws, size_t ws_size,
                              hipStream_t stream) {
    const int*   tokens = (const int*)d_in[0];
    const float* Wx     = (const float*)d_in[1];
    const float* Wh     = (const float*)d_in[2];
    const float* bias   = (const float*)d_in[3];
    const float* Wd     = (const float*)d_in[4];
    const float* bd     = (const float*)d_in[5];
    float*       out    = (float*)d_out;

    if (ws_size >= (size_t)WS_NEED) {
        uint4*  Wp  = (uint4*)((char*)d_ws + WP_OFF);
        float4* Wxp = (float4*)((char*)d_ws + WXP_OFF);
        pack_wh<<<128, 256, 0, stream>>>(Wh, Wp);
        pack_wx<<<128, 256, 0, stream>>>(Wx, bias, Wxp);
        lstm_w128<<<512 / BCR, THREADS, 0, stream>>>(tokens, Wp, Wxp, Wd, bd, out);
    } else {
        uint4* Whb = (uint4*)d_ws;
        pack_kq<<<128, 256, 0, stream>>>(Wh, Whb);
        lstm_stream<<<256, 1024, 0, stream>>>(tokens, Wx, Whb, bias, Wd, bd, out);
    }
}

// Round 3
// 1890.218 us; speedup vs baseline: 2.3219x; 1.0083x over previous
//
#include <hip/hip_runtime.h>

// LSTM char-RNN scan: B=512, SEQ=1024, UNITS=256, NUM_CHARS=128. fp32 in/out.
// Round 17: hide the update chain under the o-gate MFMAs.
//   Post-mortem r16: step=4600 cy; matrix pipe 2483 cy (floor), update chain
//   ~900-1200 cy EXPOSED (latency-bound: 5 precise divs + 5 exps per cell,
//   ~900 cy/cell proven by the r15->r16 delta), barrier/misc ~900.
//   Fixes:
//   1. MFMA loop split: pass A = i,j,f gates (48 MFMA, reg operands),
//      pass B = o gates (16 MFMA, LDS operands) issued BEFORE the c-chain.
//      MFMA is non-blocking until its acc is read -> the ~600 cy c-chain
//      (needs only i,j,f) executes while pass B drains in the matrix pipe.
//      Only the sigma(o)*tanh(c) tail (~100 cy) stays exposed.
//   2. v_rcp_f32 (__builtin_amdgcn_rcpf) replaces precise-division sequences
//      (~40 cy each, 5/cell). Rel err ~1e-6 << bf16 floor.
//   3. log2e folded into packs (i,f,o cols x log2e, j cols x 2log2e) so all
//      transcendentals are bare v_exp_f32 (exp2). forget_bias folds scaled.
// Numerics: W_h bf16 RNE (scaled pre-round), h bf16 RNE, c/gates fp32;
// expected absmax ~4.9e-4 (unchanged order).

#define U       256
#define SEQ     1024
#define NC      128
#define GDIM    1024
#define BCR     4          // batch rows per WG (at M-rows 0,4,8,12)
#define THREADS 512        // 8 waves

typedef short bf16x8 __attribute__((ext_vector_type(8)));
typedef float f32x4  __attribute__((ext_vector_type(4)));

#define WP_OFF   0                        // 512 KB packed W_h
#define WXP_OFF  (512*1024)               // 512 KB packed Wx+bias
#define WS_NEED  (1024*1024)

#define L2E   1.4426950408889634f
#define L2E2  2.8853900817779268f

#if __has_builtin(__builtin_amdgcn_exp2f)
#define EXP2(x) __builtin_amdgcn_exp2f(x)
#else
#define EXP2(x) __expf((x) * 0.6931471805599453f)
#endif
#if __has_builtin(__builtin_amdgcn_rcpf)
#define RCPF(x) __builtin_amdgcn_rcpf(x)
#else
#define RCPF(x) (1.0f / (x))
#endif

__device__ __forceinline__ float sig_(float x)  { return 1.0f / (1.0f + __expf(-x)); }
__device__ __forceinline__ float tanh_(float x) { return 1.0f - 2.0f / (__expf(2.0f * x) + 1.0f); }
__device__ __forceinline__ unsigned rne16(float f) {
    union { float f; unsigned u; } v; v.f = f;
    return (v.u + 0x7FFFu + ((v.u >> 16) & 1u)) >> 16;
}
__device__ __forceinline__ float u2f(unsigned u) {
    union { unsigned u; float f; } v; v.u = u; return v.f;
}

// ---- pack W_h into MFMA B-frag order (validated rounds 5-16) ----
// Wp[(nt*8+kt)*64 + lane]: col = nt*16+(lane&15); k = kt*32+(lane>>4)*8 + j,
// dword d packs (k=2d lo, k=2d+1 hi).  Columns pre-scaled: j-gate (cols
// 256..511) x 2log2e, others x log2e (exp2-form gates).
__global__ __launch_bounds__(256)
void pack_wh(const float* __restrict__ Wh, uint4* __restrict__ Wp) {
    int i    = blockIdx.x * 256 + threadIdx.x;   // [0, 32768)
    int lane = i & 63;
    int kt   = (i >> 6) & 7;
    int nt   = i >> 9;
    int col  = nt * 16 + (lane & 15);
    int k0   = kt * 32 + ((lane >> 4) * 8);
    const float s = (col >= 256 && col < 512) ? L2E2 : L2E;
    const float* base = Wh + (size_t)k0 * GDIM + col;
    unsigned p0 = rne16(base[0 * GDIM] * s) | (rne16(base[1 * GDIM] * s) << 16);
    unsigned p1 = rne16(base[2 * GDIM] * s) | (rne16(base[3 * GDIM] * s) << 16);
    unsigned p2 = rne16(base[4 * GDIM] * s) | (rne16(base[5 * GDIM] * s) << 16);
    unsigned p3 = rne16(base[6 * GDIM] * s) | (rne16(base[7 * GDIM] * s) << 16);
    Wp[i] = make_uint4(p0, p1, p2, p3);
}

// ---- pack Wx + bias (+forget_bias) into float4 per (x, unit), scaled ----
__global__ __launch_bounds__(256)
void pack_wx(const float* __restrict__ Wx, const float* __restrict__ bias,
             float4* __restrict__ Wxp) {
    int i = blockIdx.x * 256 + threadIdx.x;      // [0, 32768)
    int x = i >> 8, u = i & 255;
    const float* r = Wx + (size_t)x * GDIM;
    Wxp[i] = make_float4((r[u]       + bias[u])              * L2E,
                         (r[256 + u] + bias[256 + u])        * L2E2,
                         (r[512 + u] + bias[512 + u] + 1.0f) * L2E,  // forget_bias
                         (r[768 + u] + bias[768 + u])        * L2E);
}

__global__ __launch_bounds__(THREADS, 2)
void lstm_w128(const int* __restrict__ tokens,
               const uint4* __restrict__ Wp,     // packed W_h (ws)
               const float4* __restrict__ Wxp,   // packed Wx+b (ws)
               const float* __restrict__ Wd,     // [256,128]
               const float* __restrict__ bd,     // [128]
               float* __restrict__ out)          // [512,128]
{
    __shared__ uint4 LW[16][8][64];              // 128 KB  W in LDS (2 nt/wave)
    __shared__ __align__(16) short AH[2][8][64][8]; // 16 KB h bf16, double-buffered
    __shared__ int   tokw[64][4];                // 1 KB   64-step token window

    const int tid  = threadIdx.x;
    const int wv   = tid >> 6;        // wave 0..7
    const int lane = tid & 63;
    const int m    = lane & 15;
    const int quad = lane >> 4;
    const int r0   = blockIdx.x * BCR;

    // wave wv owns unit blocks {wv, 8+wv} (32 units), all 4 gates:
    // REG tiles (i,j,f both blocks): nt {wv,8+wv,16+wv,24+wv,32+wv,40+wv}.
    // LDS tiles (o gates):           nt {48+wv, 56+wv}.
    bf16x8 WR[6][8];
    #pragma unroll
    for (int jj = 0; jj < 6; ++jj)
        #pragma unroll
        for (int kt = 0; kt < 8; ++kt) {
            union { uint4 u; bf16x8 v; } c;
            c.u = Wp[((size_t)((wv + 8 * jj) * 8 + kt)) * 64 + lane];
            WR[jj][kt] = c.v;
        }
    const int slA = 2 * wv;
    #pragma unroll
    for (int kt = 0; kt < 8; ++kt) {
        LW[slA][kt][lane]     = Wp[((size_t)((48 + wv) * 8 + kt)) * 64 + lane];
        LW[slA + 1][kt][lane] = Wp[((size_t)((56 + wv) * 8 + kt)) * 64 + lane];
    }
    for (int i = tid; i < 4096; i += THREADS)    // zero both A planes (as ints)
        ((int*)AH)[i] = 0;

    // update-phase constants: EVERY lane updates batch row `quad` (M-row
    // 4*quad, acc[.][0]) of units u0 = wv*16+m and u1 = (8+wv)*16+m.
    float cst0 = 0.f, cst1 = 0.f;
    const int u0 = wv * 16 + m;
    const int u1 = (8 + wv) * 16 + m;
    const int kt0 = u0 >> 5, qa0 = (u0 >> 3) & 3, j0 = u0 & 7;
    const int kt1 = u1 >> 5, qa1 = (u1 >> 3) & 3, j1 = u1 & 7;
    const int myrow = 4 * quad;       // M-row holding this lane's batch row

    int xq = 0;                       // this step's token for batch row `quad`

    __syncthreads();

    for (int t = 0; t < SEQ; ++t) {
        if ((t & 63) == 0) {           // refresh token window (64 x 4 ints)
            if (tid < 256)
                tokw[tid >> 2][tid & 3] =
                    tokens[(size_t)(r0 + (tid & 3)) * SEQ + t + (tid >> 2)];
            __syncthreads();
            xq = tokw[0][quad];
        }
        const int p = t & 1;

        // ---- Wxp gathers for THIS step: ~300 cy L2 latency hides under the
        // MFMA passes below ----
        const float4 wxa = Wxp[(size_t)xq * 256 + u0];
        const float4 wxb = Wxp[(size_t)xq * 256 + u1];

        f32x4 acc[8];
        #pragma unroll
        for (int j = 0; j < 8; ++j) acc[j] = (f32x4){0.f, 0.f, 0.f, 0.f};

        // ---- pass A: i,j,f gates of both unit blocks (48 MFMA, reg B) ----
        // acc: [0]=iA [1]=iB [2]=jA [3]=jB [4]=fA [5]=fB
        #pragma unroll
        for (int kt = 0; kt < 8; ++kt) {
            bf16x8 ah = *(const bf16x8*)&AH[p][kt][lane][0];
            acc[0] = __builtin_amdgcn_mfma_f32_16x16x32_bf16(ah, WR[0][kt], acc[0], 0, 0, 0);
            acc[1] = __builtin_amdgcn_mfma_f32_16x16x32_bf16(ah, WR[1][kt], acc[1], 0, 0, 0);
            acc[2] = __builtin_amdgcn_mfma_f32_16x16x32_bf16(ah, WR[2][kt], acc[2], 0, 0, 0);
            acc[3] = __builtin_amdgcn_mfma_f32_16x16x32_bf16(ah, WR[3][kt], acc[3], 0, 0, 0);
            acc[4] = __builtin_amdgcn_mfma_f32_16x16x32_bf16(ah, WR[4][kt], acc[4], 0, 0, 0);
            acc[5] = __builtin_amdgcn_mfma_f32_16x16x32_bf16(ah, WR[5][kt], acc[5], 0, 0, 0);
        }

        // ---- pass B: o gates (16 MFMA, LDS B) -- issued BEFORE the c-chain
        // so the chain latency hides under these in-flight MFMAs ----
        #pragma unroll
        for (int kt = 0; kt < 8; ++kt) {
            bf16x8 ah = *(const bf16x8*)&AH[p][kt][lane][0];
            union { uint4 u; bf16x8 v; } l0, l1;
            l0.u = LW[slA][kt][lane];
            l1.u = LW[slA + 1][kt][lane];
            acc[6] = __builtin_amdgcn_mfma_f32_16x16x32_bf16(ah, l0.v, acc[6], 0, 0, 0);
            acc[7] = __builtin_amdgcn_mfma_f32_16x16x32_bf16(ah, l1.v, acc[7], 0, 0, 0);
        }

        // ---- c-chains: need only i,j,f (pass A). exp2-form gates. ----
        float thA, thB;
        {
            float gi = acc[0][0] + wxa.x;            // x log2e pre-scaled
            float gj = acc[2][0] + wxa.y;            // x 2log2e pre-scaled
            float gf = acc[4][0] + wxa.z;            // forget_bias folded
            float si = RCPF(1.0f + EXP2(-gi));
            float tj = fmaf(-2.0f, RCPF(EXP2(gj) + 1.0f), 1.0f);
            float sf = RCPF(1.0f + EXP2(-gf));
            float c  = fmaf(cst0, sf, si * tj);
            cst0 = c;
            thA = fmaf(-2.0f, RCPF(EXP2(c * L2E2) + 1.0f), 1.0f);
        }
        {
            float gi = acc[1][0] + wxb.x;
            float gj = acc[3][0] + wxb.y;
            float gf = acc[5][0] + wxb.z;
            float si = RCPF(1.0f + EXP2(-gi));
            float tj = fmaf(-2.0f, RCPF(EXP2(gj) + 1.0f), 1.0f);
            float sf = RCPF(1.0f + EXP2(-gf));
            float c  = fmaf(cst1, sf, si * tj);
            cst1 = c;
            thB = fmaf(-2.0f, RCPF(EXP2(c * L2E2) + 1.0f), 1.0f);
        }

        // ---- o-gate tails (first read of acc[6]/acc[7]) + h writes ----
        {
            float so = RCPF(1.0f + EXP2(-(acc[6][0] + wxa.w)));
            AH[p ^ 1][kt0][qa0 * 16 + myrow][j0] = (short)rne16(thA * so);
        }
        {
            float so = RCPF(1.0f + EXP2(-(acc[7][0] + wxb.w)));
            AH[p ^ 1][kt1][qa1 * 16 + myrow][j1] = (short)rne16(thB * so);
        }

        // prefetch next step's token (window-interior only)
        if (((t + 1) & 63) != 0)
            xq = tokw[(t + 1) & 63][quad];

        __syncthreads();       // single barrier: plane p^1 now visible
    }

    // ---- final dense (h is bf16 in plane 0; 4 rows x 128 cols) ----
    // batch row r lives at M-row 4r.
    for (int o = tid; o < BCR * NC; o += THREADS) {
        const int r = o >> 7;
        const int n = o & (NC - 1);
        float sum = bd[n];
        #pragma unroll 4
        for (int k = 0; k < U; ++k) {
            float hk = u2f(((unsigned)(unsigned short)
                            AH[0][k >> 5][((k >> 3) & 3) * 16 + 4 * r][k & 7]) << 16);
            sum = fmaf(hk, Wd[k * NC + n], sum);
        }
        out[(size_t)(r0 + r) * NC + n] = sum;
    }
}

// ================= fallback: round-5 streaming kernel (proven 7.6 ms) =========
__global__ __launch_bounds__(256)
void pack_kq(const float* __restrict__ Wh, uint4* __restrict__ Whb) {
    int idx = blockIdx.x * 256 + threadIdx.x;
    int kq  = idx >> 10;
    int c   = idx & 1023;
    const float* base = Wh + (size_t)(kq * 8) * GDIM + c;
    unsigned p0 = rne16(base[0 * GDIM]) | (rne16(base[1 * GDIM]) << 16);
    unsigned p1 = rne16(base[2 * GDIM]) | (rne16(base[3 * GDIM]) << 16);
    unsigned p2 = rne16(base[4 * GDIM]) | (rne16(base[5 * GDIM]) << 16);
    unsigned p3 = rne16(base[6 * GDIM]) | (rne16(base[7 * GDIM]) << 16);
    Whb[idx] = make_uint4(p0, p1, p2, p3);
}

__global__ __launch_bounds__(1024, 4)
void lstm_stream(const int* __restrict__ tokens, const float* __restrict__ Wx,
                 const uint4* __restrict__ Whb, const float* __restrict__ bias,
                 const float* __restrict__ Wd, const float* __restrict__ bd,
                 float* __restrict__ out)
{
    __shared__ float h32[2][U];
    __shared__ float G2[GDIM][2];
    __shared__ int   tok[2][SEQ];
    const int tid = threadIdx.x;
    const int r0  = blockIdx.x * 2;
    for (int i = tid; i < 2 * SEQ; i += 1024)
        ((int*)tok)[i] = tokens[r0 * SEQ + i];
    if (tid < 2 * U) ((float*)h32)[tid] = 0.0f;
    const float b_c = bias[tid];
    float c_state = 0.0f;
    const int ur = tid >> 8, uu = tid & 255;
    __syncthreads();
    const uint4* wp = Whb + tid;
    for (int t = 0; t < SEQ; ++t) {
        const int x0 = tok[0][t], x1 = tok[1][t];
        float a0e = Wx[x0 * GDIM + tid] + b_c;
        float a1e = Wx[x1 * GDIM + tid] + b_c;
        float a0o = 0.f, a1o = 0.f;
        #pragma unroll 4
        for (int kq = 0; kq < 32; ++kq) {
            float4 h0a = *(const float4*)&h32[0][kq * 8];
            float4 h0b = *(const float4*)&h32[0][kq * 8 + 4];
            float4 h1a = *(const float4*)&h32[1][kq * 8];
            float4 h1b = *(const float4*)&h32[1][kq * 8 + 4];
            uint4 wv2 = wp[kq << 10];
            float we0 = u2f(wv2.x << 16), wo0 = u2f(wv2.x & 0xffff0000u);
            float we1 = u2f(wv2.y << 16), wo1 = u2f(wv2.y & 0xffff0000u);
            float we2 = u2f(wv2.z << 16), wo2 = u2f(wv2.z & 0xffff0000u);
            float we3 = u2f(wv2.w << 16), wo3 = u2f(wv2.w & 0xffff0000u);
            a0e = fmaf(h0a.x, we0, a0e); a0o = fmaf(h0a.y, wo0, a0o);
            a1e = fmaf(h1a.x, we0, a1e); a1o = fmaf(h1a.y, wo0, a1o);
            a0e = fmaf(h0a.z, we1, a0e); a0o = fmaf(h0a.w, wo1, a0o);
            a1e = fmaf(h1a.z, we1, a1e); a1o = fmaf(h1a.w, wo1, a1o);
            a0e = fmaf(h0b.x, we2, a0e); a0o = fmaf(h0b.y, wo2, a0o);
            a1e = fmaf(h1b.x, we2, a1e); a1o = fmaf(h1b.y, wo2, a1o);
            a0e = fmaf(h0b.z, we3, a0e); a0o = fmaf(h0b.w, wo3, a0o);
            a1e = fmaf(h1b.z, we3, a1e); a1o = fmaf(h1b.w, wo3, a1o);
        }
        *(float2*)&G2[tid][0] = make_float2(a0e + a0o, a1e + a1o);
        __syncthreads();
        if (tid < 2 * U) {
            float gi = G2[uu][ur], gj = G2[U + uu][ur];
            float gf = G2[2 * U + uu][ur], go = G2[3 * U + uu][ur];
            c_state = c_state * sig_(gf + 1.0f) + sig_(gi) * tanh_(gj);
            h32[ur][uu] = tanh_(c_state) * sig_(go);
        }
        __syncthreads();
    }
    if (tid < 2 * NC) {
        const int r = tid >> 7, n = tid & (NC - 1);
        float sum = bd[n];
        #pragma unroll 4
        for (int k = 0; k < U; ++k)
            sum = fmaf(h32[r][k], Wd[k * NC + n], sum);
        out[(r0 + r) * NC + n] = sum;
    }
}

extern "C" void kernel_launch(void* const* d_in, const int* in_sizes, int n_in,
                              void* d_out, int out_size, void* d_ws, size_t ws_size,
                              hipStream_t stream) {
    const int*   tokens = (const int*)d_in[0];
    const float* Wx     = (const float*)d_in[1];
    const float* Wh     = (const float*)d_in[2];
    const float* bias   = (const float*)d_in[3];
    const float* Wd     = (const float*)d_in[4];
    const float* bd     = (const float*)d_in[5];
    float*       out    = (float*)d_out;

    if (ws_size >= (size_t)WS_NEED) {
        uint4*  Wp  = (uint4*)((char*)d_ws + WP_OFF);
        float4* Wxp = (float4*)((char*)d_ws + WXP_OFF);
        pack_wh<<<128, 256, 0, stream>>>(Wh, Wp);
        pack_wx<<<128, 256, 0, stream>>>(Wx, bias, Wxp);
        lstm_w128<<<512 / BCR, THREADS, 0, stream>>>(tokens, Wp, Wxp, Wd, bd, out);
    } else {
        uint4* Whb = (uint4*)d_ws;
        pack_kq<<<128, 256, 0, stream>>>(Wh, Whb);
        lstm_stream<<<256, 1024, 0, stream>>>(tokens, Wx, Whb, bias, Wd, bd, out);
    }
}